// Round 12
// baseline (213.454 us; speedup 1.0000x reference)
//
#include <hip/hip_runtime.h>

typedef unsigned short u16;
typedef __bf16 bf16x8 __attribute__((ext_vector_type(8)));
typedef float f32x4 __attribute__((ext_vector_type(4)));
typedef u16 u16x8 __attribute__((ext_vector_type(8)));
typedef u16 u16x4 __attribute__((ext_vector_type(4)));

typedef __attribute__((address_space(1))) const unsigned char gc_u8;
typedef __attribute__((address_space(3))) unsigned char lds_u8;

__device__ inline void gload16(const void* g, void* l) {
    __builtin_amdgcn_global_load_lds((gc_u8*)g, (lds_u8*)l, 16, 0, 0);
}
__device__ inline u16 f2bf(float f) {
    union { __bf16 h; u16 u; } c; c.h = (__bf16)f; return c.u;
}
__device__ inline float bf2f(u16 u) {
    union { u16 u[2]; float f; } c; c.u[0] = 0; c.u[1] = u; return c.f;
}
// Fully-fenced barrier: nothing (incl. register-only ops / ds ops) crosses.
__device__ inline void hard_barrier() {
    __builtin_amdgcn_sched_barrier(0);
    __builtin_amdgcn_s_barrier();
    __builtin_amdgcn_sched_barrier(0);
}
#define WAIT_LGKM0() asm volatile("s_waitcnt lgkmcnt(0)" ::: "memory")
#define WAIT_VMCNT(n) asm volatile("s_waitcnt vmcnt(" #n ")" ::: "memory")

// ---------------- merged fp32 -> bf16 converts ----------------
__global__ __launch_bounds__(256) void cvt4(const float* __restrict__ s0,
                                            const float* __restrict__ s1,
                                            const float* __restrict__ s2,
                                            const float* __restrict__ s3,
                                            u16* __restrict__ d0, u16* __restrict__ d1,
                                            u16* __restrict__ d2, u16* __restrict__ d3,
                                            int n) {
    const int y = blockIdx.y;
    const float* src = (y == 0) ? s0 : (y == 1) ? s1 : (y == 2) ? s2 : s3;
    u16* dst = (y == 0) ? d0 : (y == 1) ? d1 : (y == 2) ? d2 : d3;
    int i = (blockIdx.x * 256 + threadIdx.x) * 4;
    if (i < n) {
        float4 f = *reinterpret_cast<const float4*>(src + i);
        u16x4 u = { f2bf(f.x), f2bf(f.y), f2bf(f.z), f2bf(f.w) };
        *reinterpret_cast<u16x4*>(dst + i) = u;
    }
}
__global__ __launch_bounds__(256) void cvt3(const float* __restrict__ s0,
                                            const float* __restrict__ s1,
                                            const float* __restrict__ s2,
                                            u16* __restrict__ d0, u16* __restrict__ d1,
                                            u16* __restrict__ d2, int n) {
    const int y = blockIdx.y;
    const float* src = (y == 0) ? s0 : (y == 1) ? s1 : s2;
    u16* dst = (y == 0) ? d0 : (y == 1) ? d1 : d2;
    int i = (blockIdx.x * 256 + threadIdx.x) * 4;
    if (i < n) {
        float4 f = *reinterpret_cast<const float4*>(src + i);
        u16x4 u = { f2bf(f.x), f2bf(f.y), f2bf(f.z), f2bf(f.w) };
        *reinterpret_cast<u16x4*>(dst + i) = u;
    }
}

// ---------------- merged QKV projection GEMM (z selects matrix) — UNCHANGED ----------------
__global__ __launch_bounds__(256) void gemm_qkv(const u16* __restrict__ Aq,
                                                const u16* __restrict__ Ak,
                                                const u16* __restrict__ Av,
                                                const u16* __restrict__ Bq,
                                                const u16* __restrict__ Bk,
                                                const u16* __restrict__ Bv,
                                                const float* __restrict__ bq,
                                                const float* __restrict__ bk,
                                                const float* __restrict__ bv,
                                                u16* __restrict__ Cq,
                                                u16* __restrict__ Ck,
                                                u16* __restrict__ Cvp,
                                                int M, int N, int K) {
    __shared__ __align__(16) u16 As[2][128][32];
    __shared__ __align__(16) u16 Bs[2][128][32];
    const int z = blockIdx.z;
    const u16* A = (z == 0) ? Aq : (z == 1) ? Ak : Av;
    const u16* B = (z == 0) ? Bq : (z == 1) ? Bk : Bv;
    const float* bias = (z == 0) ? bq : (z == 1) ? bk : bv;
    u16* Cv = (z == 0) ? Cq : (z == 1) ? Ck : Cvp;
    const bool vmode = (z == 2);

    const int t = threadIdx.x, lane = t & 63, w = t >> 6;
    const int wr = w >> 1, wc = w & 1;
    const int l15 = lane & 15, l16 = lane >> 4;
    const int nwg = gridDim.x, ntiles = N >> 7;
    const int wg = blockIdx.x, chunk = nwg >> 3;
    const int swz = (wg & 7) * chunk + (wg >> 3);
    const int bm = (swz / ntiles) * 128, bn = (swz % ntiles) * 128;
    const int srow = w * 16 + (lane >> 2);
    const int sgr = (lane & 3) * 8;
    const u16* Ab = A + (size_t)bm * K;
    const u16* Bb = B + (size_t)bn * K;

    f32x4 acc[4][4];
#pragma unroll
    for (int i = 0; i < 4; i++)
#pragma unroll
        for (int j = 0; j < 4; j++) acc[i][j] = (f32x4){0.f, 0.f, 0.f, 0.f};

    auto stage = [&](int c, int k0) {
        gload16(Ab + (size_t)srow * K + k0 + sgr,        &As[c][w * 16][0]);
        gload16(Ab + (size_t)(64 + srow) * K + k0 + sgr, &As[c][64 + w * 16][0]);
        gload16(Bb + (size_t)srow * K + k0 + sgr,        &Bs[c][w * 16][0]);
        gload16(Bb + (size_t)(64 + srow) * K + k0 + sgr, &Bs[c][64 + w * 16][0]);
    };

    stage(0, 0);
    __syncthreads();

    const int NS = K >> 5;
    for (int i = 0; i < NS; ++i) {
        const int c = i & 1;
        WAIT_LGKM0();
        hard_barrier();
        if (i + 1 < NS) {
            stage(c ^ 1, (i + 1) * 32);
            WAIT_VMCNT(4);
        } else {
            WAIT_VMCNT(0);
        }
        hard_barrier();

        bf16x8 afr[4], bfr[4];
#pragma unroll
        for (int mi = 0; mi < 4; mi++)
            afr[mi] = *(const bf16x8*)&As[c][wr * 64 + mi * 16 + l15][l16 * 8];
#pragma unroll
        for (int ni = 0; ni < 4; ni++)
            bfr[ni] = *(const bf16x8*)&Bs[c][wc * 64 + ni * 16 + l15][l16 * 8];
#pragma unroll
        for (int mi = 0; mi < 4; mi++)
#pragma unroll
            for (int ni = 0; ni < 4; ni++)
                acc[mi][ni] = __builtin_amdgcn_mfma_f32_16x16x32_bf16(
                    afr[mi], bfr[ni], acc[mi][ni], 0, 0, 0);
    }

#pragma unroll
    for (int ni = 0; ni < 4; ni++) {
        const int col = bn + wc * 64 + ni * 16 + l15;
        const float bv2 = bias[col];
#pragma unroll
        for (int mi = 0; mi < 4; mi++) {
            const int r0 = bm + wr * 64 + mi * 16 + l16 * 4;
            if (vmode) {
                const int bb = r0 >> 11, ss = r0 & 2047;
                const int hh = col >> 6, dk = col & 63;
                u16x4 pk;
#pragma unroll
                for (int r = 0; r < 4; r++) pk[r] = f2bf(acc[mi][ni][r] + bv2);
                *(u16x4*)&Cv[(((size_t)(bb * 16 + hh) * 64 + dk) << 11) + ss] = pk;
            } else {
#pragma unroll
                for (int r = 0; r < 4; r++)
                    Cv[(size_t)(r0 + r) * N + col] = f2bf(acc[mi][ni][r] + bv2);
            }
        }
    }
}

// ---------------- out-projection GEMM (f32 out) — UNCHANGED ----------------
__global__ __launch_bounds__(256) void gemm_out(const u16* __restrict__ A,
                                                const u16* __restrict__ B,
                                                const float* __restrict__ bias,
                                                float* __restrict__ Cv,
                                                int M, int N, int K) {
    __shared__ __align__(16) u16 As[2][128][32];
    __shared__ __align__(16) u16 Bs[2][128][32];
    const int t = threadIdx.x, lane = t & 63, w = t >> 6;
    const int wr = w >> 1, wc = w & 1;
    const int l15 = lane & 15, l16 = lane >> 4;
    const int nwg = gridDim.x, ntiles = N >> 7;
    const int wg = blockIdx.x, chunk = nwg >> 3;
    const int swz = (wg & 7) * chunk + (wg >> 3);
    const int bm = (swz / ntiles) * 128, bn = (swz % ntiles) * 128;
    const int srow = w * 16 + (lane >> 2);
    const int sgr = (lane & 3) * 8;
    const u16* Ab = A + (size_t)bm * K;
    const u16* Bb = B + (size_t)bn * K;

    f32x4 acc[4][4];
#pragma unroll
    for (int i = 0; i < 4; i++)
#pragma unroll
        for (int j = 0; j < 4; j++) acc[i][j] = (f32x4){0.f, 0.f, 0.f, 0.f};

    auto stage = [&](int c, int k0) {
        gload16(Ab + (size_t)srow * K + k0 + sgr,        &As[c][w * 16][0]);
        gload16(Ab + (size_t)(64 + srow) * K + k0 + sgr, &As[c][64 + w * 16][0]);
        gload16(Bb + (size_t)srow * K + k0 + sgr,        &Bs[c][w * 16][0]);
        gload16(Bb + (size_t)(64 + srow) * K + k0 + sgr, &Bs[c][64 + w * 16][0]);
    };

    stage(0, 0);
    __syncthreads();

    const int NS = K >> 5;
    for (int i = 0; i < NS; ++i) {
        const int c = i & 1;
        WAIT_LGKM0();
        hard_barrier();
        if (i + 1 < NS) {
            stage(c ^ 1, (i + 1) * 32);
            WAIT_VMCNT(4);
        } else {
            WAIT_VMCNT(0);
        }
        hard_barrier();

        bf16x8 afr[4], bfr[4];
#pragma unroll
        for (int mi = 0; mi < 4; mi++)
            afr[mi] = *(const bf16x8*)&As[c][wr * 64 + mi * 16 + l15][l16 * 8];
#pragma unroll
        for (int ni = 0; ni < 4; ni++)
            bfr[ni] = *(const bf16x8*)&Bs[c][wc * 64 + ni * 16 + l15][l16 * 8];
#pragma unroll
        for (int mi = 0; mi < 4; mi++)
#pragma unroll
            for (int ni = 0; ni < 4; ni++)
                acc[mi][ni] = __builtin_amdgcn_mfma_f32_16x16x32_bf16(
                    afr[mi], bfr[ni], acc[mi][ni], 0, 0, 0);
    }

#pragma unroll
    for (int ni = 0; ni < 4; ni++) {
        const int col = bn + wc * 64 + ni * 16 + l15;
        const float bv = bias[col];
#pragma unroll
        for (int mi = 0; mi < 4; mi++) {
            const int r0 = bm + wr * 64 + mi * 16 + l16 * 4;
#pragma unroll
            for (int r = 0; r < 4; r++)
                Cv[(size_t)(r0 + r) * N + col] = acc[mi][ni][r] + bv;
        }
    }
}

// ---------------- flash attention: 2-wave blocks, 4 blocks/CU ----------------
// Block = 128 q of one (b,h); 2 waves x 64 q; KVBLK=64, dbuf + R6 fences.
// LDS 37 KB -> 4 independent blocks/CU (vs 2): barrier/lgkm stalls overlap
// across blocks (m114). Swapped-QK softmax, packed P, MFMA row-sums, exp2.
__global__ __launch_bounds__(128, 2) void attn_fwd(const u16* __restrict__ Q,
                                                   const u16* __restrict__ Kg,
                                                   const u16* __restrict__ Vt,
                                                   const int* __restrict__ mask,
                                                   u16* __restrict__ O) {
    constexpr int S = 2048, D = 1024;
    __shared__ __align__(16) u16 Kl[2][2][64][32];  // [buf][dk-half][key][dk32]
    __shared__ __align__(16) u16 Vl[2][2][64][32];  // [buf][k-half][dk][k32]
    __shared__ __align__(16) u16 Pl[2][16][68];     // per-wave P
    __shared__ unsigned Mb[64];
    const int t = threadIdx.x, lane = t & 63, w = t >> 6;   // w in {0,1}
    const int l15 = lane & 15, l16 = lane >> 4;
    const int wg = blockIdx.x;                      // 1024 blocks, %8==0 -> bijective
    const int swz = (wg & 7) * 128 + (wg >> 3);
    const int q0 = (swz & 15) * 128, h = (swz >> 4) & 15, b = swz >> 8;
    const int qb = q0 + w * 64;
    const int srow = w * 16 + (lane >> 2);          // rows 0..31 over 2 waves
    const int sgr = ((lane & 3) ^ ((lane >> 3) & 3)) * 8;   // pre-swizzled source granule
    const int gsw8 = (l16 ^ ((l15 >> 1) & 3)) * 8;          // swizzled read granule

    const u16* Khead = Kg + (size_t)b * S * D + h * 64;
    const u16* Vthead = Vt + (size_t)(b * 16 + h) * 64 * 2048;
    const int* mrow = mask + b * S;

    // 8 gloads/thread per tile (2 waves cover 64 rows in 2 chunks per section).
    // Swizzle XOR key (row>>1)&3 is invariant under row+32 (32>>1=16, 16&3=0).
    auto stage = [&](int c, int kt) {
        gload16(Khead + (size_t)(kt + srow) * D + sgr,            &Kl[c][0][w * 16][0]);
        gload16(Khead + (size_t)(kt + 32 + srow) * D + sgr,       &Kl[c][0][32 + w * 16][0]);
        gload16(Khead + (size_t)(kt + srow) * D + 32 + sgr,       &Kl[c][1][w * 16][0]);
        gload16(Khead + (size_t)(kt + 32 + srow) * D + 32 + sgr,  &Kl[c][1][32 + w * 16][0]);
        gload16(Vthead + (size_t)srow * 2048 + kt + sgr,          &Vl[c][0][w * 16][0]);
        gload16(Vthead + (size_t)(32 + srow) * 2048 + kt + sgr,   &Vl[c][0][32 + w * 16][0]);
        gload16(Vthead + (size_t)srow * 2048 + kt + 32 + sgr,     &Vl[c][1][w * 16][0]);
        gload16(Vthead + (size_t)(32 + srow) * 2048 + kt + 32 + sgr, &Vl[c][1][32 + w * 16][0]);
    };

    stage(0, 0);
    // pack mask bits (once): 16 iters x 2 waves x 64 lanes = 2048 keys
#pragma unroll
    for (int j = 0; j < 16; j++) {
        unsigned long long bal = __ballot(mrow[j * 128 + w * 64 + lane] != 0);
        if (lane == 0) {
            Mb[(j * 2 + w) * 2]     = (unsigned)bal;
            Mb[(j * 2 + w) * 2 + 1] = (unsigned)(bal >> 32);
        }
    }

    // Q fragments (4 q-subtiles), pre-scaled by 0.125 * log2(e)
    constexpr float QSCALE = 0.125f * 1.44269504f;
    bf16x8 aq[4][2];
#pragma unroll
    for (int qt = 0; qt < 4; qt++)
#pragma unroll
        for (int ks = 0; ks < 2; ks++) {
            const size_t qi = ((size_t)b * S + qb + qt * 16 + l15) * D +
                              h * 64 + ks * 32 + l16 * 8;
            u16x8 raw = *(const u16x8*)&Q[qi];
            bf16x8 qv;
#pragma unroll
            for (int i = 0; i < 8; i++) qv[i] = (__bf16)(bf2f(raw[i]) * QSCALE);
            aq[qt][ks] = qv;
        }

    bf16x8 ones;
#pragma unroll
    for (int i = 0; i < 8; i++) ones[i] = (__bf16)1.0f;

    f32x4 acc[4][4];
    f32x4 accl[4];
#pragma unroll
    for (int qt = 0; qt < 4; qt++) {
        accl[qt] = (f32x4){0.f, 0.f, 0.f, 0.f};
#pragma unroll
        for (int dt = 0; dt < 4; dt++) acc[qt][dt] = (f32x4){0.f, 0.f, 0.f, 0.f};
    }

    __syncthreads();  // one-time full drain (vm+lgkm): buf0 staged, Mb visible,
                      // Q-loads retired -> in-loop vmcnt counts stage loads only

    for (int tile = 0; tile < S / 64; ++tile) {
        const int c = tile & 1;
        const int cur = tile * 64;
        WAIT_LGKM0();     // our LDS reads fully retired before anyone overwrites
        hard_barrier();   // barrier1
        if (tile + 1 < S / 64) {
            stage(c ^ 1, cur + 64);
            WAIT_VMCNT(8);   // 8 newest = next tile's -> current tile landed
        } else {
            WAIT_VMCNT(0);
        }
        hard_barrier();   // barrier2

        // hoist K and V fragments (16 b128)
        bf16x8 kf0[4], kf1[4], vf0[4], vf1[4];
#pragma unroll
        for (int k4 = 0; k4 < 4; k4++) {
            kf0[k4] = *(const bf16x8*)&Kl[c][0][k4 * 16 + l15][gsw8];
            kf1[k4] = *(const bf16x8*)&Kl[c][1][k4 * 16 + l15][gsw8];
        }
#pragma unroll
        for (int dt = 0; dt < 4; dt++) {
            vf0[dt] = *(const bf16x8*)&Vl[c][0][dt * 16 + l15][gsw8];
            vf1[dt] = *(const bf16x8*)&Vl[c][1][dt * 16 + l15][gsw8];
        }

        // mask adds: key = cur + k4*16 + l16*4 + r
        const unsigned w0 = Mb[cur >> 5], w1 = Mb[(cur >> 5) + 1];
        float madd[4][4];
#pragma unroll
        for (int k4 = 0; k4 < 4; k4++) {
            const unsigned wsel = (k4 < 2) ? w0 : w1;
            const unsigned bits = (wsel >> ((k4 & 1) * 16 + l16 * 4)) & 0xFu;
#pragma unroll
            for (int r = 0; r < 4; r++)
                madd[k4][r] = ((bits >> r) & 1u) ? 0.f : -1.0e9f;
        }

#pragma unroll
        for (int qt = 0; qt < 4; qt++) {
            __builtin_amdgcn_s_setprio(1);
            f32x4 z[4];
#pragma unroll
            for (int k4 = 0; k4 < 4; k4++) {
                z[k4] = (f32x4){0.f, 0.f, 0.f, 0.f};
                z[k4] = __builtin_amdgcn_mfma_f32_16x16x32_bf16(kf0[k4], aq[qt][0], z[k4], 0, 0, 0);
                z[k4] = __builtin_amdgcn_mfma_f32_16x16x32_bf16(kf1[k4], aq[qt][1], z[k4], 0, 0, 0);
            }
            __builtin_amdgcn_s_setprio(0);
#pragma unroll
            for (int k4 = 0; k4 < 4; k4++) {
                u16x4 pk;
#pragma unroll
                for (int r = 0; r < 4; r++)
                    pk[r] = f2bf(__builtin_amdgcn_exp2f(z[k4][r] + madd[k4][r]));
                *(u16x4*)&Pl[w][l15][k4 * 16 + l16 * 4] = pk;  // packed b64
            }
            bf16x8 pa0 = *(const bf16x8*)&Pl[w][l15][l16 * 8];
            bf16x8 pa1 = *(const bf16x8*)&Pl[w][l15][32 + l16 * 8];
            __builtin_amdgcn_s_setprio(1);
            accl[qt] = __builtin_amdgcn_mfma_f32_16x16x32_bf16(pa0, ones, accl[qt], 0, 0, 0);
            accl[qt] = __builtin_amdgcn_mfma_f32_16x16x32_bf16(pa1, ones, accl[qt], 0, 0, 0);
#pragma unroll
            for (int dt = 0; dt < 4; dt++) {
                acc[qt][dt] = __builtin_amdgcn_mfma_f32_16x16x32_bf16(
                    pa0, vf0[dt], acc[qt][dt], 0, 0, 0);
                acc[qt][dt] = __builtin_amdgcn_mfma_f32_16x16x32_bf16(
                    pa1, vf1[dt], acc[qt][dt], 0, 0, 0);
            }
            __builtin_amdgcn_s_setprio(0);
        }
    }

    // epilogue: accl[qt][r] = row sum for q = qt*16 + l16*4 + r
#pragma unroll
    for (int qt = 0; qt < 4; qt++) {
        f32x4 inv;
#pragma unroll
        for (int r = 0; r < 4; r++) inv[r] = 1.f / accl[qt][r];
#pragma unroll
        for (int dt = 0; dt < 4; dt++)
#pragma unroll
            for (int r = 0; r < 4; r++) {
                const int tok = qb + qt * 16 + l16 * 4 + r;
                O[((size_t)b * S + tok) * D + h * 64 + dt * 16 + l15] =
                    f2bf(acc[qt][dt][r] * inv[r]);
            }
    }
}

extern "C" void kernel_launch(void* const* d_in, const int* in_sizes, int n_in,
                              void* d_out, int out_size, void* d_ws, size_t ws_size,
                              hipStream_t stream) {
    const float* query = (const float*)d_in[0];
    const float* key   = (const float*)d_in[1];
    const float* value = (const float*)d_in[2];
    const int*   mask  = (const int*)d_in[3];
    const float* Wq = (const float*)d_in[4];
    const float* bq = (const float*)d_in[5];
    const float* Wk = (const float*)d_in[6];
    const float* bk = (const float*)d_in[7];
    const float* Wv = (const float*)d_in[8];
    const float* bv = (const float*)d_in[9];
    const float* Wo = (const float*)d_in[10];
    const float* bo = (const float*)d_in[11];
    float* out = (float*)d_out;

    constexpr int S = 2048, D = 1024;
    constexpr size_t MSZ = (size_t)4 * S * D;   // 8388608
    constexpr size_t WSZ = (size_t)D * D;       // 1048576
    const size_t need = 4 * WSZ * 2 + 4 * MSZ * 2;  // 72 MB
    if (ws_size < need) return;

    char* p = (char*)d_ws;
    u16* Wqb = (u16*)p; p += WSZ * 2;
    u16* Wkb = (u16*)p; p += WSZ * 2;
    u16* Wvb = (u16*)p; p += WSZ * 2;
    u16* Wob = (u16*)p; p += WSZ * 2;
    u16* Aq  = (u16*)p; p += MSZ * 2;  // bf16 query activation; later reused as Xb
    u16* Qb  = (u16*)p; p += MSZ * 2;
    u16* Kb  = (u16*)p; p += MSZ * 2;
    u16* Vtb = (u16*)p; p += MSZ * 2;  // (b,h,dk,s)
    u16* Ak = (u16*)d_out;             // d_out as scratch (fully rewritten at end)
    u16* Av = (u16*)d_out + MSZ;
    u16* Xb = Aq;

    cvt4<<<dim3(WSZ / 1024, 4), 256, 0, stream>>>(Wq, Wk, Wv, Wo,
                                                  Wqb, Wkb, Wvb, Wob, (int)WSZ);
    cvt3<<<dim3(MSZ / 1024, 3), 256, 0, stream>>>(query, key, value,
                                                  Aq, Ak, Av, (int)MSZ);
    gemm_qkv<<<dim3(512, 1, 3), 256, 0, stream>>>(Aq, Ak, Av, Wqb, Wkb, Wvb,
                                                  bq, bk, bv, Qb, Kb, Vtb,
                                                  8192, 1024, 1024);
    attn_fwd<<<1024, 128, 0, stream>>>(Qb, Kb, Vtb, mask, Xb);
    gemm_out<<<512, 256, 0, stream>>>(Xb, Wob, bo, out, 8192, 1024, 1024);
}

// Round 13
// 192.066 us; speedup vs baseline: 1.1114x; 1.1114x over previous
//
#include <hip/hip_runtime.h>

typedef unsigned short u16;
typedef __bf16 bf16x8 __attribute__((ext_vector_type(8)));
typedef float f32x4 __attribute__((ext_vector_type(4)));
typedef u16 u16x8 __attribute__((ext_vector_type(8)));
typedef u16 u16x4 __attribute__((ext_vector_type(4)));

typedef __attribute__((address_space(1))) const unsigned char gc_u8;
typedef __attribute__((address_space(3))) unsigned char lds_u8;

__device__ inline void gload16(const void* g, void* l) {
    __builtin_amdgcn_global_load_lds((gc_u8*)g, (lds_u8*)l, 16, 0, 0);
}
__device__ inline u16 f2bf(float f) {
    union { __bf16 h; u16 u; } c; c.h = (__bf16)f; return c.u;
}
__device__ inline float bf2f(u16 u) {
    union { u16 u[2]; float f; } c; c.u[0] = 0; c.u[1] = u; return c.f;
}
// Fully-fenced barrier: nothing (incl. register-only ops / ds ops) crosses.
__device__ inline void hard_barrier() {
    __builtin_amdgcn_sched_barrier(0);
    __builtin_amdgcn_s_barrier();
    __builtin_amdgcn_sched_barrier(0);
}
#define WAIT_LGKM0() asm volatile("s_waitcnt lgkmcnt(0)" ::: "memory")
#define WAIT_VMCNT(n) asm volatile("s_waitcnt vmcnt(" #n ")" ::: "memory")

// ---------------- weight fp32 -> bf16 convert ----------------
__global__ __launch_bounds__(256) void cvt4(const float* __restrict__ s0,
                                            const float* __restrict__ s1,
                                            const float* __restrict__ s2,
                                            const float* __restrict__ s3,
                                            u16* __restrict__ d0, u16* __restrict__ d1,
                                            u16* __restrict__ d2, u16* __restrict__ d3,
                                            int n) {
    const int y = blockIdx.y;
    const float* src = (y == 0) ? s0 : (y == 1) ? s1 : (y == 2) ? s2 : s3;
    u16* dst = (y == 0) ? d0 : (y == 1) ? d1 : (y == 2) ? d2 : d3;
    int i = (blockIdx.x * 256 + threadIdx.x) * 4;
    if (i < n) {
        float4 f = *reinterpret_cast<const float4*>(src + i);
        u16x4 u = { f2bf(f.x), f2bf(f.y), f2bf(f.z), f2bf(f.w) };
        *reinterpret_cast<u16x4*>(dst + i) = u;
    }
}

// ---------------- merged QKV projection GEMM, f32-A direct ----------------
// C = A[M,K](f32) * B[N,K]^T(bf16) + bias. A staged as f32 via global_load_lds
// into XOR-swizzled LDS (key=row&7, 16B granules), converted to bf16 at
// fragment-load (same RNE cast as the old cvt pass -> bit-identical output).
// z==0,1: bf16 [M][N] out. z==2: bf16 V^T head layout (b,h,dk,s).
__global__ __launch_bounds__(256) void gemm_qkv(const float* __restrict__ Aq,
                                                const float* __restrict__ Ak,
                                                const float* __restrict__ Av,
                                                const u16* __restrict__ Bq,
                                                const u16* __restrict__ Bk,
                                                const u16* __restrict__ Bv,
                                                const float* __restrict__ bq,
                                                const float* __restrict__ bk,
                                                const float* __restrict__ bv,
                                                u16* __restrict__ Cq,
                                                u16* __restrict__ Ck,
                                                u16* __restrict__ Cvp,
                                                int M, int N, int K) {
    __shared__ __align__(16) float Asf[2][128][32];  // 32 KB
    __shared__ __align__(16) u16 Bs[2][128][32];     // 16 KB
    const int z = blockIdx.z;
    const float* A = (z == 0) ? Aq : (z == 1) ? Ak : Av;
    const u16* B = (z == 0) ? Bq : (z == 1) ? Bk : Bv;
    const float* bias = (z == 0) ? bq : (z == 1) ? bk : bv;
    u16* Cv = (z == 0) ? Cq : (z == 1) ? Ck : Cvp;
    const bool vmode = (z == 2);

    const int t = threadIdx.x, lane = t & 63, w = t >> 6;
    const int wr = w >> 1, wc = w & 1;
    const int l15 = lane & 15, l16 = lane >> 4;
    const int nwg = gridDim.x, ntiles = N >> 7;
    const int wg = blockIdx.x, chunk = nwg >> 3;
    const int swz = (wg & 7) * chunk + (wg >> 3);
    const int bm = (swz / ntiles) * 128, bn = (swz % ntiles) * 128;
    const int srow = w * 16 + (lane >> 2);               // B staging row
    const int sgr = (lane & 3) * 8;                      // B staging granule (bf16)
    const int arsub = lane >> 3;                         // A staging sub-row 0..7
    const int agr = ((lane & 7) ^ (lane >> 3)) * 4;      // A source granule (f32, pre-swizzled)
    const u16* Bb = B + (size_t)bn * K;

    f32x4 acc[4][4];
#pragma unroll
    for (int i = 0; i < 4; i++)
#pragma unroll
        for (int j = 0; j < 4; j++) acc[i][j] = (f32x4){0.f, 0.f, 0.f, 0.f};

    // A: 4 gloads/thread (32 f32-rows each, swizzled source); B: 2 gloads.
    auto stage = [&](int c, int k0) {
#pragma unroll
        for (int ch = 0; ch < 4; ch++)
            gload16(A + (size_t)(bm + ch * 32 + w * 8 + arsub) * K + k0 + agr,
                    &Asf[c][ch * 32 + w * 8][0]);
        gload16(Bb + (size_t)srow * K + k0 + sgr,        &Bs[c][w * 16][0]);
        gload16(Bb + (size_t)(64 + srow) * K + k0 + sgr, &Bs[c][64 + w * 16][0]);
    };

    stage(0, 0);
    __syncthreads();  // one-time full drain: buf0 staged

    const int NS = K >> 5;
    for (int i = 0; i < NS; ++i) {
        const int c = i & 1;
        WAIT_LGKM0();     // our LDS reads fully retired before buffers flip
        hard_barrier();   // barrier1
        if (i + 1 < NS) {
            stage(c ^ 1, (i + 1) * 32);
            WAIT_VMCNT(6);   // 6 newest = next tile's -> current tile landed
        } else {
            WAIT_VMCNT(0);
        }
        hard_barrier();   // barrier2

        const int key = l15 & 7;
        bf16x8 afr[4], bfr[4];
#pragma unroll
        for (int mi = 0; mi < 4; mi++) {
            const int rr = wr * 64 + mi * 16 + l15;
            f32x4 lo = *(const f32x4*)&Asf[c][rr][((2 * l16) ^ key) * 4];
            f32x4 hi = *(const f32x4*)&Asf[c][rr][((2 * l16 + 1) ^ key) * 4];
            bf16x8 v;
            v[0] = (__bf16)lo[0]; v[1] = (__bf16)lo[1];
            v[2] = (__bf16)lo[2]; v[3] = (__bf16)lo[3];
            v[4] = (__bf16)hi[0]; v[5] = (__bf16)hi[1];
            v[6] = (__bf16)hi[2]; v[7] = (__bf16)hi[3];
            afr[mi] = v;
        }
#pragma unroll
        for (int ni = 0; ni < 4; ni++)
            bfr[ni] = *(const bf16x8*)&Bs[c][wc * 64 + ni * 16 + l15][l16 * 8];
#pragma unroll
        for (int mi = 0; mi < 4; mi++)
#pragma unroll
            for (int ni = 0; ni < 4; ni++)
                acc[mi][ni] = __builtin_amdgcn_mfma_f32_16x16x32_bf16(
                    afr[mi], bfr[ni], acc[mi][ni], 0, 0, 0);
    }

#pragma unroll
    for (int ni = 0; ni < 4; ni++) {
        const int col = bn + wc * 64 + ni * 16 + l15;
        const float bv2 = bias[col];
#pragma unroll
        for (int mi = 0; mi < 4; mi++) {
            const int r0 = bm + wr * 64 + mi * 16 + l16 * 4;
            if (vmode) {  // V^T head layout (b,h,dk,s), 4 tokens packed
                const int bb = r0 >> 11, ss = r0 & 2047;
                const int hh = col >> 6, dk = col & 63;
                u16x4 pk;
#pragma unroll
                for (int r = 0; r < 4; r++) pk[r] = f2bf(acc[mi][ni][r] + bv2);
                *(u16x4*)&Cv[(((size_t)(bb * 16 + hh) * 64 + dk) << 11) + ss] = pk;
            } else {
#pragma unroll
                for (int r = 0; r < 4; r++)
                    Cv[(size_t)(r0 + r) * N + col] = f2bf(acc[mi][ni][r] + bv2);
            }
        }
    }
}

// ---------------- out-projection GEMM (f32 out) — R6-proven, UNCHANGED ----------------
__global__ __launch_bounds__(256) void gemm_out(const u16* __restrict__ A,
                                                const u16* __restrict__ B,
                                                const float* __restrict__ bias,
                                                float* __restrict__ Cv,
                                                int M, int N, int K) {
    __shared__ __align__(16) u16 As[2][128][32];
    __shared__ __align__(16) u16 Bs[2][128][32];
    const int t = threadIdx.x, lane = t & 63, w = t >> 6;
    const int wr = w >> 1, wc = w & 1;
    const int l15 = lane & 15, l16 = lane >> 4;
    const int nwg = gridDim.x, ntiles = N >> 7;
    const int wg = blockIdx.x, chunk = nwg >> 3;
    const int swz = (wg & 7) * chunk + (wg >> 3);
    const int bm = (swz / ntiles) * 128, bn = (swz % ntiles) * 128;
    const int srow = w * 16 + (lane >> 2);
    const int sgr = (lane & 3) * 8;
    const u16* Ab = A + (size_t)bm * K;
    const u16* Bb = B + (size_t)bn * K;

    f32x4 acc[4][4];
#pragma unroll
    for (int i = 0; i < 4; i++)
#pragma unroll
        for (int j = 0; j < 4; j++) acc[i][j] = (f32x4){0.f, 0.f, 0.f, 0.f};

    auto stage = [&](int c, int k0) {
        gload16(Ab + (size_t)srow * K + k0 + sgr,        &As[c][w * 16][0]);
        gload16(Ab + (size_t)(64 + srow) * K + k0 + sgr, &As[c][64 + w * 16][0]);
        gload16(Bb + (size_t)srow * K + k0 + sgr,        &Bs[c][w * 16][0]);
        gload16(Bb + (size_t)(64 + srow) * K + k0 + sgr, &Bs[c][64 + w * 16][0]);
    };

    stage(0, 0);
    __syncthreads();

    const int NS = K >> 5;
    for (int i = 0; i < NS; ++i) {
        const int c = i & 1;
        WAIT_LGKM0();
        hard_barrier();
        if (i + 1 < NS) {
            stage(c ^ 1, (i + 1) * 32);
            WAIT_VMCNT(4);
        } else {
            WAIT_VMCNT(0);
        }
        hard_barrier();

        bf16x8 afr[4], bfr[4];
#pragma unroll
        for (int mi = 0; mi < 4; mi++)
            afr[mi] = *(const bf16x8*)&As[c][wr * 64 + mi * 16 + l15][l16 * 8];
#pragma unroll
        for (int ni = 0; ni < 4; ni++)
            bfr[ni] = *(const bf16x8*)&Bs[c][wc * 64 + ni * 16 + l15][l16 * 8];
#pragma unroll
        for (int mi = 0; mi < 4; mi++)
#pragma unroll
            for (int ni = 0; ni < 4; ni++)
                acc[mi][ni] = __builtin_amdgcn_mfma_f32_16x16x32_bf16(
                    afr[mi], bfr[ni], acc[mi][ni], 0, 0, 0);
    }

#pragma unroll
    for (int ni = 0; ni < 4; ni++) {
        const int col = bn + wc * 64 + ni * 16 + l15;
        const float bv = bias[col];
#pragma unroll
        for (int mi = 0; mi < 4; mi++) {
            const int r0 = bm + wr * 64 + mi * 16 + l16 * 4;
#pragma unroll
            for (int r = 0; r < 4; r++)
                Cv[(size_t)(r0 + r) * N + col] = acc[mi][ni][r] + bv;
        }
    }
}

// ---------------- flash attention — EXACT R11 version (measured 102.4 us) ----------------
__global__ __launch_bounds__(256, 2) void attn_fwd(const u16* __restrict__ Q,
                                                   const u16* __restrict__ Kg,
                                                   const u16* __restrict__ Vt,
                                                   const int* __restrict__ mask,
                                                   u16* __restrict__ O) {
    constexpr int S = 2048, D = 1024;
    __shared__ __align__(16) u16 Kl[2][2][2][64][32];  // [buf][kg][dk-half][key64][dk32]
    __shared__ __align__(16) u16 Vl[2][2][2][64][32];  // [buf][kg][k32-half][dk64][k32]
    __shared__ __align__(16) u16 Pl[4][16][68];
    __shared__ unsigned Mb[64];
    const int t = threadIdx.x, lane = t & 63, w = t >> 6;
    const int l15 = lane & 15, l16 = lane >> 4;
    const int wg = blockIdx.x;                         // 512 blocks, %8==0 -> bijective
    const int swz = (wg & 7) * 64 + (wg >> 3);
    const int q0 = (swz & 7) * 256, h = (swz >> 3) & 15, b = swz >> 7;
    const int qb = q0 + w * 64;
    const int srow = w * 16 + (lane >> 2);
    const int sgr = ((lane & 3) ^ ((lane >> 3) & 3)) * 8;   // pre-swizzled source granule
    const int gsw8 = (l16 ^ ((l15 >> 1) & 3)) * 8;          // swizzled read granule

    const u16* Khead = Kg + (size_t)b * S * D + h * 64;
    const u16* Vthead = Vt + (size_t)(b * 16 + h) * 64 * 2048;
    const int* mrow = mask + b * S;

    auto stage = [&](int c, int kt) {
#pragma unroll
        for (int kg = 0; kg < 2; kg++) {
            const int k0 = kt + kg * 64;
            gload16(Khead + (size_t)(k0 + srow) * D + sgr,        &Kl[c][kg][0][w * 16][0]);
            gload16(Khead + (size_t)(k0 + srow) * D + 32 + sgr,   &Kl[c][kg][1][w * 16][0]);
            gload16(Vthead + (size_t)srow * 2048 + k0 + sgr,      &Vl[c][kg][0][w * 16][0]);
            gload16(Vthead + (size_t)srow * 2048 + k0 + 32 + sgr, &Vl[c][kg][1][w * 16][0]);
        }
    };

    stage(0, 0);
    // pack mask bits (once)
#pragma unroll
    for (int j = 0; j < 8; j++) {
        unsigned long long bal = __ballot(mrow[j * 256 + w * 64 + lane] != 0);
        if (lane == 0) {
            Mb[(j * 4 + w) * 2]     = (unsigned)bal;
            Mb[(j * 4 + w) * 2 + 1] = (unsigned)(bal >> 32);
        }
    }

    // Q fragments (4 q-subtiles), pre-scaled by 0.125 * log2(e)
    constexpr float QSCALE = 0.125f * 1.44269504f;
    bf16x8 aq[4][2];
#pragma unroll
    for (int qt = 0; qt < 4; qt++)
#pragma unroll
        for (int ks = 0; ks < 2; ks++) {
            const size_t qi = ((size_t)b * S + qb + qt * 16 + l15) * D +
                              h * 64 + ks * 32 + l16 * 8;
            u16x8 raw = *(const u16x8*)&Q[qi];
            bf16x8 qv;
#pragma unroll
            for (int i = 0; i < 8; i++) qv[i] = (__bf16)(bf2f(raw[i]) * QSCALE);
            aq[qt][ks] = qv;
        }

    bf16x8 ones;
#pragma unroll
    for (int i = 0; i < 8; i++) ones[i] = (__bf16)1.0f;

    f32x4 acc[4][4];
    f32x4 accl[4];
#pragma unroll
    for (int qt = 0; qt < 4; qt++) {
        accl[qt] = (f32x4){0.f, 0.f, 0.f, 0.f};
#pragma unroll
        for (int dt = 0; dt < 4; dt++) acc[qt][dt] = (f32x4){0.f, 0.f, 0.f, 0.f};
    }

    __syncthreads();  // one-time full drain: buf0 staged + Mb visible

    for (int tile = 0; tile < S / 128; ++tile) {
        const int c = tile & 1;
        const int cur = tile * 128;
        WAIT_LGKM0();     // our LDS reads fully retired before anyone overwrites
        hard_barrier();   // barrier1
        if (tile + 1 < S / 128) {
            stage(c ^ 1, cur + 128);
            WAIT_VMCNT(8);   // 8 newest = next tile's loads -> current tile landed
        } else {
            WAIT_VMCNT(0);
        }
        hard_barrier();   // barrier2

#pragma unroll
        for (int kg = 0; kg < 2; kg++) {
            bf16x8 kf0[4], kf1[4], vf0[4], vf1[4];
#pragma unroll
            for (int k4 = 0; k4 < 4; k4++) {
                kf0[k4] = *(const bf16x8*)&Kl[c][kg][0][k4 * 16 + l15][gsw8];
                kf1[k4] = *(const bf16x8*)&Kl[c][kg][1][k4 * 16 + l15][gsw8];
            }
#pragma unroll
            for (int dt = 0; dt < 4; dt++) {
                vf0[dt] = *(const bf16x8*)&Vl[c][kg][0][dt * 16 + l15][gsw8];
                vf1[dt] = *(const bf16x8*)&Vl[c][kg][1][dt * 16 + l15][gsw8];
            }

            // mask adds: key = cur + kg*64 + k4*16 + l16*4 + r
            const int mb0 = (cur >> 5) + kg * 2;
            const unsigned w0 = Mb[mb0], w1 = Mb[mb0 + 1];
            float madd[4][4];
#pragma unroll
            for (int k4 = 0; k4 < 4; k4++) {
                const unsigned wsel = (k4 < 2) ? w0 : w1;
                const unsigned bits = (wsel >> ((k4 & 1) * 16 + l16 * 4)) & 0xFu;
#pragma unroll
                for (int r = 0; r < 4; r++)
                    madd[k4][r] = ((bits >> r) & 1u) ? 0.f : -1.0e9f;
            }

#pragma unroll
            for (int qt = 0; qt < 4; qt++) {
#pragma unroll
                for (int k4 = 0; k4 < 4; k4++) {
                    f32x4 z = (f32x4){0.f, 0.f, 0.f, 0.f};
                    z = __builtin_amdgcn_mfma_f32_16x16x32_bf16(kf0[k4], aq[qt][0], z, 0, 0, 0);
                    z = __builtin_amdgcn_mfma_f32_16x16x32_bf16(kf1[k4], aq[qt][1], z, 0, 0, 0);
                    u16x4 pk;
#pragma unroll
                    for (int r = 0; r < 4; r++)
                        pk[r] = f2bf(__builtin_amdgcn_exp2f(z[r] + madd[k4][r]));
                    *(u16x4*)&Pl[w][l15][k4 * 16 + l16 * 4] = pk;  // packed b64
                }
                bf16x8 pa0 = *(const bf16x8*)&Pl[w][l15][l16 * 8];
                bf16x8 pa1 = *(const bf16x8*)&Pl[w][l15][32 + l16 * 8];
                accl[qt] = __builtin_amdgcn_mfma_f32_16x16x32_bf16(pa0, ones, accl[qt], 0, 0, 0);
                accl[qt] = __builtin_amdgcn_mfma_f32_16x16x32_bf16(pa1, ones, accl[qt], 0, 0, 0);
#pragma unroll
                for (int dt = 0; dt < 4; dt++) {
                    acc[qt][dt] = __builtin_amdgcn_mfma_f32_16x16x32_bf16(
                        pa0, vf0[dt], acc[qt][dt], 0, 0, 0);
                    acc[qt][dt] = __builtin_amdgcn_mfma_f32_16x16x32_bf16(
                        pa1, vf1[dt], acc[qt][dt], 0, 0, 0);
                }
            }
        }
    }

    // epilogue: accl[qt][r] = row sum for q = qt*16 + l16*4 + r
#pragma unroll
    for (int qt = 0; qt < 4; qt++) {
        f32x4 inv;
#pragma unroll
        for (int r = 0; r < 4; r++) inv[r] = 1.f / accl[qt][r];
#pragma unroll
        for (int dt = 0; dt < 4; dt++)
#pragma unroll
            for (int r = 0; r < 4; r++) {
                const int tok = qb + qt * 16 + l16 * 4 + r;
                O[((size_t)b * S + tok) * D + h * 64 + dt * 16 + l15] =
                    f2bf(acc[qt][dt][r] * inv[r]);
            }
    }
}

extern "C" void kernel_launch(void* const* d_in, const int* in_sizes, int n_in,
                              void* d_out, int out_size, void* d_ws, size_t ws_size,
                              hipStream_t stream) {
    const float* query = (const float*)d_in[0];
    const float* key   = (const float*)d_in[1];
    const float* value = (const float*)d_in[2];
    const int*   mask  = (const int*)d_in[3];
    const float* Wq = (const float*)d_in[4];
    const float* bq = (const float*)d_in[5];
    const float* Wk = (const float*)d_in[6];
    const float* bk = (const float*)d_in[7];
    const float* Wv = (const float*)d_in[8];
    const float* bv = (const float*)d_in[9];
    const float* Wo = (const float*)d_in[10];
    const float* bo = (const float*)d_in[11];
    float* out = (float*)d_out;

    constexpr int S = 2048, D = 1024;
    constexpr size_t MSZ = (size_t)4 * S * D;   // 8388608
    constexpr size_t WSZ = (size_t)D * D;       // 1048576
    const size_t need = 4 * WSZ * 2 + 4 * MSZ * 2;  // 72 MB
    if (ws_size < need) return;

    char* p = (char*)d_ws;
    u16* Wqb = (u16*)p; p += WSZ * 2;
    u16* Wkb = (u16*)p; p += WSZ * 2;
    u16* Wvb = (u16*)p; p += WSZ * 2;
    u16* Wob = (u16*)p; p += WSZ * 2;
    u16* Xb  = (u16*)p; p += MSZ * 2;  // attn output
    u16* Qb  = (u16*)p; p += MSZ * 2;
    u16* Kb  = (u16*)p; p += MSZ * 2;
    u16* Vtb = (u16*)p; p += MSZ * 2;  // (b,h,dk,s)

    cvt4<<<dim3(WSZ / 1024, 4), 256, 0, stream>>>(Wq, Wk, Wv, Wo,
                                                  Wqb, Wkb, Wvb, Wob, (int)WSZ);
    gemm_qkv<<<dim3(512, 1, 3), 256, 0, stream>>>(query, key, value,
                                                  Wqb, Wkb, Wvb, bq, bk, bv,
                                                  Qb, Kb, Vtb, 8192, 1024, 1024);
    attn_fwd<<<512, 256, 0, stream>>>(Qb, Kb, Vtb, mask, Xb);
    gemm_out<<<512, 256, 0, stream>>>(Xb, Wob, bo, out, 8192, 1024, 1024);
}